// Round 1
// baseline (360.322 us; speedup 1.0000x reference)
//
#include <hip/hip_runtime.h>
#include <stdint.h>

typedef _Float16 f16;
typedef f16 f16x8 __attribute__((ext_vector_type(8)));
typedef float f32x4 __attribute__((ext_vector_type(4)));

#define MFMA(a,b,c) __builtin_amdgcn_mfma_f32_16x16x32_f16(a, b, c, 0, 0, 0)

// fast sigmoid: v_exp + v_rcp (no IEEE divide sequence; tolerance is huge)
__device__ __forceinline__ float sigmoidf_(float z) {
  return __builtin_amdgcn_rcpf(1.0f + __expf(-z));
}

// ---------------------------------------------------------------------------
// prep: scale[b]; weights -> f16; zero out[0..63].
// Wcat = [Aq;Ak;Av] (192x2048). Wsm = 9 x (64x64): Aq1,Ak1,Av1,Aq5,Ak5,Av5,Ao,Ao1,Ao5
// ---------------------------------------------------------------------------
__global__ void prep_kernel(const float* __restrict__ L,
    const float* __restrict__ Aq, const float* __restrict__ Ak, const float* __restrict__ Av,
    const float* __restrict__ Aq1, const float* __restrict__ Ak1, const float* __restrict__ Av1,
    const float* __restrict__ Aq5, const float* __restrict__ Ak5, const float* __restrict__ Av5,
    const float* __restrict__ Ao, const float* __restrict__ Ao1, const float* __restrict__ Ao5,
    float* __restrict__ scale, f16* __restrict__ Wcat, f16* __restrict__ Wsm,
    float* __restrict__ out)
{
  __shared__ float r4[4];
  int blk = blockIdx.x, t = threadIdx.x;
  if (blk < 64) {
    float v = (L[blk * 512 + t] >= 1.0f) ? 1.0f : 0.0f;
    #pragma unroll
    for (int off = 32; off; off >>= 1) v += __shfl_down(v, off);
    if ((t & 63) == 0) r4[t >> 6] = v;
    __syncthreads();
    if (t == 0) scale[blk] = sqrtf(r4[0] + r4[1] + r4[2] + r4[3] + 1.0f);
  } else if (blk < 160) {
    int base = (blk - 64) * 4096;
    for (int i = 0; i < 16; i++) {
      int idx = base + t + i * 256;
      int row = idx >> 11, col = idx & 2047;
      float v = (row < 64) ? Aq[row * 2048 + col]
              : (row < 128) ? Ak[(row - 64) * 2048 + col]
              : Av[(row - 128) * 2048 + col];
      Wcat[idx] = (f16)v;
    }
  } else if (blk < 169) {
    int j = blk - 160;
    const float* s = (j == 0) ? Aq1 : (j == 1) ? Ak1 : (j == 2) ? Av1 : (j == 3) ? Aq5
                   : (j == 4) ? Ak5 : (j == 5) ? Av5 : (j == 6) ? Ao : (j == 7) ? Ao1 : Ao5;
    for (int i = 0; i < 16; i++) { int idx = t + i * 256; Wsm[j * 4096 + idx] = (f16)s[idx]; }
  } else {
    if (t < 64) out[t] = 0.0f;
  }
}

// ---------------------------------------------------------------------------
// qkv1: per (b, n-group of 32): Out[n][r] = sigmoid( sum_f x[b,f,n]*Wcat[r,f] )
// r: 0-63 -> Qt[b][n][r], 64-127 -> Kt[b][n][r-64], 128-191 -> V[b][r-128][n]
// grid (8,64) = 512 blocks -> 2 blocks/CU, 8 waves/CU.
// Register double-buffer: chunk k+1's global loads issue during chunk k's
// MFMA phase so HBM latency hides under compute (loads can't cross s_barrier
// on their own).
// ---------------------------------------------------------------------------
__global__ __launch_bounds__(256) void qkv1_kernel(const float* __restrict__ x,
    const f16* __restrict__ Wcat, f16* __restrict__ Qt, f16* __restrict__ Kt,
    f16* __restrict__ Vg)
{
  int b = blockIdx.y, n0 = blockIdx.x * 32;
  int t = threadIdx.x, lane = t & 63, w = t >> 6;
  int l15 = lane & 15, q = lane >> 4;
  __shared__ f16 xt[32 * 72];    // x^T tile [n][f]
  __shared__ f16 wt[192 * 72];   // W tile [r][f]
  f32x4 acc[2][3] = {};
  const float* xb = x + (size_t)b * 524288 + n0;
  int tn = t & 31, fg = t >> 5;

  float xr[8];
  uint4  wr[6];

  auto load_x = [&](int f0) {
    #pragma unroll
    for (int rep = 0; rep < 4; rep++) {
      int fl = fg * 8 + rep * 2;
      xr[rep * 2]     = xb[(size_t)(f0 + fl) * 256 + tn];
      xr[rep * 2 + 1] = xb[(size_t)(f0 + fl + 1) * 256 + tn];
    }
  };
  auto load_w = [&](int f0) {
    #pragma unroll
    for (int i = 0; i < 6; i++) {
      int id = t + i * 256, r = id >> 3, c = id & 7;
      wr[i] = *(const uint4*)(Wcat + (size_t)r * 2048 + f0 + c * 8);
    }
  };

  load_x(0);
  load_w(0);

  for (int f0 = 0; f0 < 2048; f0 += 64) {
    // stage prefetched regs -> LDS
    #pragma unroll
    for (int rep = 0; rep < 4; rep++) {
      int fl = fg * 8 + rep * 2;
      uint32_t pk = (uint32_t)__builtin_bit_cast(uint16_t, (f16)xr[rep * 2])
                  | ((uint32_t)__builtin_bit_cast(uint16_t, (f16)xr[rep * 2 + 1]) << 16);
      *(uint32_t*)&xt[tn * 72 + fl] = pk;
    }
    #pragma unroll
    for (int i = 0; i < 6; i++) {
      int id = t + i * 256, r = id >> 3, c = id & 7;
      *(uint4*)&wt[r * 72 + c * 8] = wr[i];
    }
    __syncthreads();
    // issue next chunk's global loads now; latency overlaps the MFMA phase
    if (f0 + 64 < 2048) { load_x(f0 + 64); load_w(f0 + 64); }
    #pragma unroll
    for (int ks = 0; ks < 2; ks++) {
      int k0 = ks * 32 + q * 8;
      f16x8 af[2], bf[3];
      af[0] = *(const f16x8*)&xt[l15 * 72 + k0];
      af[1] = *(const f16x8*)&xt[(16 + l15) * 72 + k0];
      #pragma unroll
      for (int j = 0; j < 3; j++) bf[j] = *(const f16x8*)&wt[((w * 3 + j) * 16 + l15) * 72 + k0];
      #pragma unroll
      for (int nt = 0; nt < 2; nt++)
        #pragma unroll
        for (int j = 0; j < 3; j++)
          acc[nt][j] = MFMA(af[nt], bf[j], acc[nt][j]);
    }
    __syncthreads();
  }
  #pragma unroll
  for (int nt = 0; nt < 2; nt++)
    #pragma unroll
    for (int j = 0; j < 3; j++) {
      int rr = (w * 3 + j) * 16 + l15;
      float s[4];
      #pragma unroll
      for (int reg = 0; reg < 4; reg++) s[reg] = sigmoidf_(acc[nt][j][reg]);
      int nbase = n0 + nt * 16 + q * 4;
      if (rr < 64) {
        #pragma unroll
        for (int reg = 0; reg < 4; reg++)
          Qt[(size_t)b * 16384 + (size_t)(nbase + reg) * 64 + rr] = (f16)s[reg];
      } else if (rr < 128) {
        #pragma unroll
        for (int reg = 0; reg < 4; reg++)
          Kt[(size_t)b * 16384 + (size_t)(nbase + reg) * 64 + (rr - 64)] = (f16)s[reg];
      } else {
        union { f16 h[4]; uint2 u; } pk;
        #pragma unroll
        for (int reg = 0; reg < 4; reg++) pk.h[reg] = (f16)s[reg];
        *(uint2*)(Vg + (size_t)b * 16384 + (size_t)(rr - 128) * 256 + nbase) = pk.u;
      }
    }
}

// ---------------------------------------------------------------------------
// attnB<LAYER>: grid (4,64), 512 threads (8 waves). Block (g,b) owns query
// rows n0=g*64..n0+63. Full K^T/V (all 256 cols) in LDS (K/V recomputed 4x
// for l>0). No chunking: S is [64][256]. LDS ~126 KB.
// Layouts: KT [256][72], SM = M^T [256][72] (l>0) then S4 [64][264],
// VM [64][264], QT [64][72] (later M' staging [64][64]), OT [64][72].
// ---------------------------------------------------------------------------
template<int LAYER>
__global__ __launch_bounds__(512) void attnB_kernel(const float* __restrict__ x,
    const float* __restrict__ scale, const f16* __restrict__ Wsm,
    const f16* __restrict__ Qtg, const f16* __restrict__ Ktg, const f16* __restrict__ Vgg,
    const f16* __restrict__ Min, f16* __restrict__ Mout, float* __restrict__ out)
{
  int g = blockIdx.x, b = blockIdx.y, n0 = g * 64;
  int t = threadIdx.x, lane = t & 63, w = t >> 6;
  int l15 = lane & 15, q = lane >> 4;
  __shared__ f16 KT[256 * 72];
  __shared__ f16 SM[256 * 72];
  __shared__ f16 VM[64 * 264];
  __shared__ f16 QT[64 * 72];
  __shared__ f16 OT[64 * 72];
  __shared__ float denomS[64];

  float sinv = __builtin_amdgcn_rcpf(scale[b]);
  if (t < 64) denomS[t] = 0.0f;

  if (LAYER == 0) {
    const uint4* qs = (const uint4*)(Qtg + (size_t)b * 16384 + (size_t)n0 * 64);
    { int n = t >> 3, c = t & 7; *(uint4*)&QT[n * 72 + c * 8] = qs[t]; }
    const uint4* ks = (const uint4*)(Ktg + (size_t)b * 16384);
    const uint4* vs = (const uint4*)(Vgg + (size_t)b * 16384);
    #pragma unroll
    for (int i = 0; i < 4; i++) {
      int id = t + i * 512;
      int m = id >> 3, c = id & 7;
      *(uint4*)&KT[m * 72 + c * 8] = ks[id];
      int r = id >> 5, c2 = id & 31;
      *(uint4*)&VM[r * 264 + c2 * 8] = vs[id];
    }
  } else {
    const uint4* ms = (const uint4*)(Min + (size_t)b * 16384);
    #pragma unroll
    for (int i = 0; i < 4; i++) {
      int id = t + i * 512, m = id >> 3, c = id & 7;
      *(uint4*)&SM[m * 72 + c * 8] = ms[id];
    }
  }
  __syncthreads();

  const f16* Wq = Wsm + (size_t)(LAYER == 1 ? 0 : 3) * 4096;
  const f16* Wk = Wsm + (size_t)(LAYER == 1 ? 1 : 4) * 4096;
  const f16* Wv = Wsm + (size_t)(LAYER == 1 ? 2 : 5) * 4096;
  const f16* Wo = Wsm + (size_t)(LAYER == 0 ? 6 : (LAYER == 1 ? 7 : 8)) * 4096;

  if (LAYER > 0) {
    if (w < 4) {
      // KT[m][r] = sigmoid( sum_s M^T[m][s] * Wk[r][s] ), mt = w*4..w*4+3
      f16x8 bk[4][2];
      #pragma unroll
      for (int rt = 0; rt < 4; rt++) {
        bk[rt][0] = *(const f16x8*)(Wk + (rt * 16 + l15) * 64 + q * 8);
        bk[rt][1] = *(const f16x8*)(Wk + (rt * 16 + l15) * 64 + 32 + q * 8);
      }
      #pragma unroll
      for (int mi = 0; mi < 4; mi++) {
        int mt = w * 4 + mi;
        f16x8 a0 = *(const f16x8*)&SM[(mt * 16 + l15) * 72 + q * 8];
        f16x8 a1 = *(const f16x8*)&SM[(mt * 16 + l15) * 72 + 32 + q * 8];
        #pragma unroll
        for (int rt = 0; rt < 4; rt++) {
          f32x4 acc = {}; acc = MFMA(a0, bk[rt][0], acc); acc = MFMA(a1, bk[rt][1], acc);
          #pragma unroll
          for (int reg = 0; reg < 4; reg++)
            KT[(mt * 16 + q * 4 + reg) * 72 + rt * 16 + l15] = (f16)sigmoidf_(acc[reg]);
        }
      }
    } else {
      // VM[r][m] = sigmoid( sum_s Wv[r][s] * M^T[m][s] ), mt = (w-4)*4..
      f16x8 av[4][2];
      #pragma unroll
      for (int rt = 0; rt < 4; rt++) {
        av[rt][0] = *(const f16x8*)(Wv + (rt * 16 + l15) * 64 + q * 8);
        av[rt][1] = *(const f16x8*)(Wv + (rt * 16 + l15) * 64 + 32 + q * 8);
      }
      #pragma unroll
      for (int mi = 0; mi < 4; mi++) {
        int mt = (w - 4) * 4 + mi;
        f16x8 b0 = *(const f16x8*)&SM[(mt * 16 + l15) * 72 + q * 8];
        f16x8 b1 = *(const f16x8*)&SM[(mt * 16 + l15) * 72 + 32 + q * 8];
        #pragma unroll
        for (int rt = 0; rt < 4; rt++) {
          f32x4 acc = {}; acc = MFMA(av[rt][0], b0, acc); acc = MFMA(av[rt][1], b1, acc);
          #pragma unroll
          for (int reg = 0; reg < 4; reg++)
            VM[(rt * 16 + q * 4 + reg) * 264 + mt * 16 + l15] = (f16)sigmoidf_(acc[reg]);
        }
      }
    }
    // QT[n][r] for local rows: nt = w>>1, rt = (w&1)*2 + {0,1}
    {
      int nt = w >> 1;
      f16x8 a0 = *(const f16x8*)&SM[(n0 + nt * 16 + l15) * 72 + q * 8];
      f16x8 a1 = *(const f16x8*)&SM[(n0 + nt * 16 + l15) * 72 + 32 + q * 8];
      #pragma unroll
      for (int j = 0; j < 2; j++) {
        int rt = (w & 1) * 2 + j;
        f16x8 b0 = *(const f16x8*)(Wq + (rt * 16 + l15) * 64 + q * 8);
        f16x8 b1 = *(const f16x8*)(Wq + (rt * 16 + l15) * 64 + 32 + q * 8);
        f32x4 acc = {}; acc = MFMA(a0, b0, acc); acc = MFMA(a1, b1, acc);
        #pragma unroll
        for (int reg = 0; reg < 4; reg++)
          QT[(nt * 16 + q * 4 + reg) * 72 + rt * 16 + l15] = (f16)sigmoidf_(acc[reg]);
      }
    }
    __syncthreads();
  }

  // S = exp(QK^T * sinv): wave w -> nt = w>>1, mt = (w&1)*8 .. +7; denom via shfl+LDS atomic
  {
    int nt = w >> 1;
    f16x8 a0 = *(const f16x8*)&QT[(nt * 16 + l15) * 72 + q * 8];
    f16x8 a1 = *(const f16x8*)&QT[(nt * 16 + l15) * 72 + 32 + q * 8];
    float dsum[4] = {0.f, 0.f, 0.f, 0.f};
    #pragma unroll
    for (int mi = 0; mi < 8; mi++) {
      int mt = (w & 1) * 8 + mi;
      f16x8 b0 = *(const f16x8*)&KT[(mt * 16 + l15) * 72 + q * 8];
      f16x8 b1 = *(const f16x8*)&KT[(mt * 16 + l15) * 72 + 32 + q * 8];
      f32x4 acc = {}; acc = MFMA(a0, b0, acc); acc = MFMA(a1, b1, acc);
      #pragma unroll
      for (int reg = 0; reg < 4; reg++) {
        float e = __expf(acc[reg] * sinv);
        dsum[reg] += e;
        SM[(nt * 16 + q * 4 + reg) * 264 + mt * 16 + l15] = (f16)e;
      }
    }
    #pragma unroll
    for (int reg = 0; reg < 4; reg++) {
      #pragma unroll
      for (int mask = 1; mask < 16; mask <<= 1) dsum[reg] += __shfl_xor(dsum[reg], mask);
    }
    if (l15 == 0) {
      #pragma unroll
      for (int reg = 0; reg < 4; reg++) atomicAdd(&denomS[nt * 16 + q * 4 + reg], dsum[reg]);
    }
  }
  __syncthreads();

  // AV: o^T[n][r] = sum_m S4[n][m] VM[r][m]; normalize by 1/denom (v_rcp) -> OT
  {
    int nt = w >> 1;
    f32x4 oacc[2] = {};
    #pragma unroll
    for (int kc = 0; kc < 8; kc++) {
      f16x8 af = *(const f16x8*)&SM[(nt * 16 + l15) * 264 + kc * 32 + q * 8];
      #pragma unroll
      for (int j = 0; j < 2; j++) {
        int rt = (w & 1) * 2 + j;
        f16x8 bf = *(const f16x8*)&VM[(rt * 16 + l15) * 264 + kc * 32 + q * 8];
        oacc[j] = MFMA(af, bf, oacc[j]);
      }
    }
    float rden[4];
    #pragma unroll
    for (int reg = 0; reg < 4; reg++)
      rden[reg] = __builtin_amdgcn_rcpf(denomS[nt * 16 + q * 4 + reg]);
    #pragma unroll
    for (int j = 0; j < 2; j++) {
      int rt = (w & 1) * 2 + j;
      #pragma unroll
      for (int reg = 0; reg < 4; reg++) {
        int row = nt * 16 + q * 4 + reg;
        OT[row * 72 + rt * 16 + l15] = (f16)(oacc[j][reg] * rden[reg]);
      }
    }
  }
  __syncthreads();

  // M'[n][s] = silu( sum_r OT[n][r] Wo[s][r] ) -> Mst (QT reused, stride 64)
  f16* Mst = QT;
  {
    int nt = w >> 1;
    f16x8 a0 = *(const f16x8*)&OT[(nt * 16 + l15) * 72 + q * 8];
    f16x8 a1 = *(const f16x8*)&OT[(nt * 16 + l15) * 72 + 32 + q * 8];
    #pragma unroll
    for (int j = 0; j < 2; j++) {
      int st = (w & 1) * 2 + j;
      f16x8 b0 = *(const f16x8*)(Wo + (st * 16 + l15) * 64 + q * 8);
      f16x8 b1 = *(const f16x8*)(Wo + (st * 16 + l15) * 64 + 32 + q * 8);
      f32x4 acc = {}; acc = MFMA(a0, b0, acc); acc = MFMA(a1, b1, acc);
      #pragma unroll
      for (int reg = 0; reg < 4; reg++) {
        float z = acc[reg];
        Mst[(nt * 16 + q * 4 + reg) * 64 + st * 16 + l15] = (f16)(z * sigmoidf_(z));
      }
    }
  }
  __syncthreads();

  if (LAYER < 2) {
    int row = t >> 3, c = t & 7;
    *(uint4*)(Mout + (size_t)b * 16384 + (size_t)(n0 + row) * 64 + c * 8)
        = *(const uint4*)&Mst[row * 64 + c * 8];
  } else {
    float contrib = 0.0f;
    if (t < 64) {
      int ntok = n0 + t;
      const f16* row = &Mst[t * 64];
      float d[4] = {0, 0, 0, 0}, pp = 0.0f;
      #pragma unroll
      for (int gg = 0; gg < 8; gg++) {
        f16x8 v = *(const f16x8*)(row + gg * 8);
        float ss = 0.0f;
        #pragma unroll
        for (int k = 0; k < 8; k++) { float f = (float)v[k]; ss += f * f; }
        if (gg < 4) d[gg] = ss; else pp += ss;
      }
      int np = ntok >> 1, c0 = (ntok & 1) * 2;
      const float* xb = x + (size_t)b * 524288 + (size_t)c0 * 256;
      float q1a = xb[np], q1b = xb[256 + np];
      float q2a = xb[128 + np], q2b = xb[384 + np];
      contrib = d[0] * (q1a * q1a + q1b * q1b)
              + (d[1] + d[2]) * (q1a * q2a + q1b * q2b)
              + d[3] * (q2a * q2a + q2b * q2b) + pp;
    }
    if (w == 0) {
      #pragma unroll
      for (int off = 32; off; off >>= 1) contrib += __shfl_down(contrib, off);
      if (lane == 0) atomicAdd(out + b, contrib);
    }
  }
}

// ---------------------------------------------------------------------------
extern "C" void kernel_launch(void* const* d_in, const int* in_sizes, int n_in,
                              void* d_out, int out_size, void* d_ws, size_t ws_size,
                              hipStream_t stream) {
  const float* x   = (const float*)d_in[0];
  const float* L   = (const float*)d_in[1];
  const float* Aq  = (const float*)d_in[2];
  const float* Ak  = (const float*)d_in[3];
  const float* Av  = (const float*)d_in[4];
  const float* Aq1 = (const float*)d_in[5];
  const float* Ak1 = (const float*)d_in[6];
  const float* Av1 = (const float*)d_in[7];
  const float* Aq5 = (const float*)d_in[8];
  const float* Ak5 = (const float*)d_in[9];
  const float* Av5 = (const float*)d_in[10];
  const float* Ao  = (const float*)d_in[11];
  const float* Ao1 = (const float*)d_in[12];
  const float* Ao5 = (const float*)d_in[13];

  char* ws = (char*)d_ws;
  float* scale = (float*)ws;
  f16* Wcat  = (f16*)(ws + 256);
  f16* Wsm   = (f16*)(ws + 786688);
  f16* Qtg   = (f16*)(ws + 860416);
  f16* Ktg   = (f16*)(ws + 2957568);
  f16* Vgg   = (f16*)(ws + 5054720);
  f16* MbufA = (f16*)(ws + 7151872);
  f16* MbufB = (f16*)(ws + 9249024);
  float* out = (float*)d_out;

  prep_kernel<<<170, 256, 0, stream>>>(L, Aq, Ak, Av, Aq1, Ak1, Av1,
                                       Aq5, Ak5, Av5, Ao, Ao1, Ao5, scale, Wcat, Wsm, out);
  qkv1_kernel<<<dim3(8, 64), 256, 0, stream>>>(x, Wcat, Qtg, Ktg, Vgg);
  attnB_kernel<0><<<dim3(4, 64), 512, 0, stream>>>(x, scale, Wsm, Qtg, Ktg, Vgg,
                                                   nullptr, MbufA, out);
  attnB_kernel<1><<<dim3(4, 64), 512, 0, stream>>>(x, scale, Wsm, Qtg, Ktg, Vgg,
                                                   MbufA, MbufB, out);
  attnB_kernel<2><<<dim3(4, 64), 512, 0, stream>>>(x, scale, Wsm, Qtg, Ktg, Vgg,
                                                   MbufB, nullptr, out);
}

// Round 3
// 265.404 us; speedup vs baseline: 1.3576x; 1.3576x over previous
//
#include <hip/hip_runtime.h>
#include <stdint.h>

typedef _Float16 f16;
typedef f16 f16x8 __attribute__((ext_vector_type(8)));
typedef float f32x4 __attribute__((ext_vector_type(4)));

#define MFMA(a,b,c) __builtin_amdgcn_mfma_f32_16x16x32_f16(a, b, c, 0, 0, 0)

// fast sigmoid: v_exp + v_rcp (no IEEE divide sequence; tolerance is huge)
__device__ __forceinline__ float sigmoidf_(float z) {
  return __builtin_amdgcn_rcpf(1.0f + __expf(-z));
}

// ---------------------------------------------------------------------------
// prep: scale[b]; weights -> f16; zero out[0..63].
// Wcat = [Aq;Ak;Av] (192x2048). Wsm = 9 x (64x64): Aq1,Ak1,Av1,Aq5,Ak5,Av5,Ao,Ao1,Ao5
// ---------------------------------------------------------------------------
__global__ void prep_kernel(const float* __restrict__ L,
    const float* __restrict__ Aq, const float* __restrict__ Ak, const float* __restrict__ Av,
    const float* __restrict__ Aq1, const float* __restrict__ Ak1, const float* __restrict__ Av1,
    const float* __restrict__ Aq5, const float* __restrict__ Ak5, const float* __restrict__ Av5,
    const float* __restrict__ Ao, const float* __restrict__ Ao1, const float* __restrict__ Ao5,
    float* __restrict__ scale, f16* __restrict__ Wcat, f16* __restrict__ Wsm,
    float* __restrict__ out)
{
  __shared__ float r4[4];
  int blk = blockIdx.x, t = threadIdx.x;
  if (blk < 64) {
    float v = (L[blk * 512 + t] >= 1.0f) ? 1.0f : 0.0f;
    #pragma unroll
    for (int off = 32; off; off >>= 1) v += __shfl_down(v, off);
    if ((t & 63) == 0) r4[t >> 6] = v;
    __syncthreads();
    if (t == 0) scale[blk] = sqrtf(r4[0] + r4[1] + r4[2] + r4[3] + 1.0f);
  } else if (blk < 160) {
    int base = (blk - 64) * 4096;
    for (int i = 0; i < 16; i++) {
      int idx = base + t + i * 256;
      int row = idx >> 11, col = idx & 2047;
      float v = (row < 64) ? Aq[row * 2048 + col]
              : (row < 128) ? Ak[(row - 64) * 2048 + col]
              : Av[(row - 128) * 2048 + col];
      Wcat[idx] = (f16)v;
    }
  } else if (blk < 169) {
    int j = blk - 160;
    const float* s = (j == 0) ? Aq1 : (j == 1) ? Ak1 : (j == 2) ? Av1 : (j == 3) ? Aq5
                   : (j == 4) ? Ak5 : (j == 5) ? Av5 : (j == 6) ? Ao : (j == 7) ? Ao1 : Ao5;
    for (int i = 0; i < 16; i++) { int idx = t + i * 256; Wsm[j * 4096 + idx] = (f16)s[idx]; }
  } else {
    if (t < 64) out[t] = 0.0f;
  }
}

// ---------------------------------------------------------------------------
// qkv1: per (b, n-group of 32): Out[n][r] = sigmoid( sum_f x[b,f,n]*Wcat[r,f] )
// r: 0-63 -> Qt[b][n][r], 64-127 -> Kt[b][n][r-64], 128-191 -> V[b][r-128][n]
// grid (8,64) = 512 blocks -> 2 blocks/CU.
// 2-phase pipeline, T14 split: issue tile t+1's global loads into NAMED
// registers (xa0..xa7, wr0..wr5 -- no arrays, no scratch) before the MFMA
// phase on tile t; ds_write them after the MFMA reads; ONE barrier/iter.
// All LDS tiles padded to stride 72 -> conflict-free (8 lanes / 4-bank group).
// ---------------------------------------------------------------------------
__global__ __launch_bounds__(256) void qkv1_kernel(const float* __restrict__ x,
    const f16* __restrict__ Wcat, f16* __restrict__ Qt, f16* __restrict__ Kt,
    f16* __restrict__ Vg)
{
  int b = blockIdx.y, n0 = blockIdx.x * 32;
  int t = threadIdx.x, lane = t & 63, w = t >> 6;
  int l15 = lane & 15, q = lane >> 4;
  __shared__ f16 xt[2][32 * 72];     // x^T tile [n][f]
  __shared__ f16 wt[2][192 * 72];    // W tile [r][f]
  f32x4 acc[2][3] = {};
  const float* xb = x + (size_t)b * 524288 + n0;
  int tn = t & 31, fg = t >> 5;      // thread owns x rows fg*8..fg*8+7, col tn

  // per-thread W-tile coords: 6 uint4 loads x 256 threads cover 192 rows x 64 cols
  int r0 = t >> 3,           c0 = t & 7;
  int r1 = (t + 256) >> 3,   c1 = (t + 256) & 7;
  int r2 = (t + 512) >> 3,   c2 = (t + 512) & 7;
  int r3 = (t + 768) >> 3,   c3 = (t + 768) & 7;
  int r4 = (t + 1024) >> 3,  c4 = (t + 1024) & 7;
  int r5 = (t + 1280) >> 3,  c5 = (t + 1280) & 7;
  const f16* pw0 = Wcat + (size_t)r0 * 2048 + c0 * 8;
  const f16* pw1 = Wcat + (size_t)r1 * 2048 + c1 * 8;
  const f16* pw2 = Wcat + (size_t)r2 * 2048 + c2 * 8;
  const f16* pw3 = Wcat + (size_t)r3 * 2048 + c3 * 8;
  const f16* pw4 = Wcat + (size_t)r4 * 2048 + c4 * 8;
  const f16* pw5 = Wcat + (size_t)r5 * 2048 + c5 * 8;
  const float* px = xb + (size_t)(fg * 8) * 256 + tn;

  float xa0, xa1, xa2, xa3, xa4, xa5, xa6, xa7;
  uint4 wr0, wr1, wr2, wr3, wr4, wr5;

#define LOAD_X(f0n) do {                                                        \
    const float* xp_ = px + (size_t)(f0n) * 256;                                \
    xa0 = xp_[0];    xa1 = xp_[256];  xa2 = xp_[512];  xa3 = xp_[768];          \
    xa4 = xp_[1024]; xa5 = xp_[1280]; xa6 = xp_[1536]; xa7 = xp_[1792];         \
  } while (0)

#define LOAD_W(f0n) do {                                                        \
    wr0 = *(const uint4*)(pw0 + (f0n)); wr1 = *(const uint4*)(pw1 + (f0n));     \
    wr2 = *(const uint4*)(pw2 + (f0n)); wr3 = *(const uint4*)(pw3 + (f0n));     \
    wr4 = *(const uint4*)(pw4 + (f0n)); wr5 = *(const uint4*)(pw5 + (f0n));     \
  } while (0)

#define WRITE_XW(buf) do {                                                      \
    f16x8 pk_;                                                                  \
    pk_[0] = (f16)xa0; pk_[1] = (f16)xa1; pk_[2] = (f16)xa2; pk_[3] = (f16)xa3; \
    pk_[4] = (f16)xa4; pk_[5] = (f16)xa5; pk_[6] = (f16)xa6; pk_[7] = (f16)xa7; \
    *(f16x8*)&xt[buf][tn * 72 + fg * 8] = pk_;                                  \
    f16* wb_ = &wt[buf][0];                                                     \
    *(uint4*)&wb_[r0 * 72 + c0 * 8] = wr0;                                      \
    *(uint4*)&wb_[r1 * 72 + c1 * 8] = wr1;                                      \
    *(uint4*)&wb_[r2 * 72 + c2 * 8] = wr2;                                      \
    *(uint4*)&wb_[r3 * 72 + c3 * 8] = wr3;                                      \
    *(uint4*)&wb_[r4 * 72 + c4 * 8] = wr4;                                      \
    *(uint4*)&wb_[r5 * 72 + c5 * 8] = wr5;                                      \
  } while (0)

  // prologue: stage tile 0
  LOAD_X(0);
  LOAD_W(0);
  WRITE_XW(0);
  __syncthreads();

  int cur = 0;
  for (int f0 = 0; f0 < 2048; f0 += 64) {
    int nxt = cur ^ 1;
    bool more = (f0 + 64 < 2048);
    if (more) { LOAD_X(f0 + 64); LOAD_W(f0 + 64); }   // HBM latency hides under MFMA

    #pragma unroll
    for (int ks = 0; ks < 2; ks++) {
      int k0 = ks * 32 + q * 8;
      f16x8 af[2], bf[3];
      af[0] = *(const f16x8*)&xt[cur][l15 * 72 + k0];
      af[1] = *(const f16x8*)&xt[cur][(16 + l15) * 72 + k0];
      #pragma unroll
      for (int j = 0; j < 3; j++) bf[j] = *(const f16x8*)&wt[cur][((w * 3 + j) * 16 + l15) * 72 + k0];
      #pragma unroll
      for (int nt = 0; nt < 2; nt++)
        #pragma unroll
        for (int j = 0; j < 3; j++)
          acc[nt][j] = MFMA(af[nt], bf[j], acc[nt][j]);
    }

    if (more) WRITE_XW(nxt);   // regs -> LDS after this tile's ds_reads
    __syncthreads();
    cur = nxt;
  }
#undef LOAD_X
#undef LOAD_W
#undef WRITE_XW

  #pragma unroll
  for (int nt = 0; nt < 2; nt++)
    #pragma unroll
    for (int j = 0; j < 3; j++) {
      int rr = (w * 3 + j) * 16 + l15;
      float s[4];
      #pragma unroll
      for (int reg = 0; reg < 4; reg++) s[reg] = sigmoidf_(acc[nt][j][reg]);
      int nbase = n0 + nt * 16 + q * 4;
      if (rr < 64) {
        #pragma unroll
        for (int reg = 0; reg < 4; reg++)
          Qt[(size_t)b * 16384 + (size_t)(nbase + reg) * 64 + rr] = (f16)s[reg];
      } else if (rr < 128) {
        #pragma unroll
        for (int reg = 0; reg < 4; reg++)
          Kt[(size_t)b * 16384 + (size_t)(nbase + reg) * 64 + (rr - 64)] = (f16)s[reg];
      } else {
        union { f16 h[4]; uint2 u; } pk;
        #pragma unroll
        for (int reg = 0; reg < 4; reg++) pk.h[reg] = (f16)s[reg];
        *(uint2*)(Vg + (size_t)b * 16384 + (size_t)(rr - 128) * 256 + nbase) = pk.u;
      }
    }
}

// ---------------------------------------------------------------------------
// attnB<LAYER>: grid (4,64), 512 threads (8 waves). Block (g,b) owns query
// rows n0=g*64..n0+63. Full K^T/V (all 256 cols) in LDS (K/V recomputed 4x
// for l>0). No chunking: S is [64][256]. LDS ~126 KB.
// Layouts: KT [256][72], SM = M^T [256][72] (l>0) then S4 [64][264],
// VM [64][264], QT [64][72] (later M' staging [64][64]), OT [64][72].
// ---------------------------------------------------------------------------
template<int LAYER>
__global__ __launch_bounds__(512) void attnB_kernel(const float* __restrict__ x,
    const float* __restrict__ scale, const f16* __restrict__ Wsm,
    const f16* __restrict__ Qtg, const f16* __restrict__ Ktg, const f16* __restrict__ Vgg,
    const f16* __restrict__ Min, f16* __restrict__ Mout, float* __restrict__ out)
{
  int g = blockIdx.x, b = blockIdx.y, n0 = g * 64;
  int t = threadIdx.x, lane = t & 63, w = t >> 6;
  int l15 = lane & 15, q = lane >> 4;
  __shared__ f16 KT[256 * 72];
  __shared__ f16 SM[256 * 72];
  __shared__ f16 VM[64 * 264];
  __shared__ f16 QT[64 * 72];
  __shared__ f16 OT[64 * 72];
  __shared__ float denomS[64];

  float sinv = __builtin_amdgcn_rcpf(scale[b]);
  if (t < 64) denomS[t] = 0.0f;

  if (LAYER == 0) {
    const uint4* qs = (const uint4*)(Qtg + (size_t)b * 16384 + (size_t)n0 * 64);
    { int n = t >> 3, c = t & 7; *(uint4*)&QT[n * 72 + c * 8] = qs[t]; }
    const uint4* ks = (const uint4*)(Ktg + (size_t)b * 16384);
    const uint4* vs = (const uint4*)(Vgg + (size_t)b * 16384);
    #pragma unroll
    for (int i = 0; i < 4; i++) {
      int id = t + i * 512;
      int m = id >> 3, c = id & 7;
      *(uint4*)&KT[m * 72 + c * 8] = ks[id];
      int r = id >> 5, c2 = id & 31;
      *(uint4*)&VM[r * 264 + c2 * 8] = vs[id];
    }
  } else {
    const uint4* ms = (const uint4*)(Min + (size_t)b * 16384);
    #pragma unroll
    for (int i = 0; i < 4; i++) {
      int id = t + i * 512, m = id >> 3, c = id & 7;
      *(uint4*)&SM[m * 72 + c * 8] = ms[id];
    }
  }
  __syncthreads();

  const f16* Wq = Wsm + (size_t)(LAYER == 1 ? 0 : 3) * 4096;
  const f16* Wk = Wsm + (size_t)(LAYER == 1 ? 1 : 4) * 4096;
  const f16* Wv = Wsm + (size_t)(LAYER == 1 ? 2 : 5) * 4096;
  const f16* Wo = Wsm + (size_t)(LAYER == 0 ? 6 : (LAYER == 1 ? 7 : 8)) * 4096;

  if (LAYER > 0) {
    if (w < 4) {
      // KT[m][r] = sigmoid( sum_s M^T[m][s] * Wk[r][s] ), mt = w*4..w*4+3
      f16x8 bk[4][2];
      #pragma unroll
      for (int rt = 0; rt < 4; rt++) {
        bk[rt][0] = *(const f16x8*)(Wk + (rt * 16 + l15) * 64 + q * 8);
        bk[rt][1] = *(const f16x8*)(Wk + (rt * 16 + l15) * 64 + 32 + q * 8);
      }
      #pragma unroll
      for (int mi = 0; mi < 4; mi++) {
        int mt = w * 4 + mi;
        f16x8 a0 = *(const f16x8*)&SM[(mt * 16 + l15) * 72 + q * 8];
        f16x8 a1 = *(const f16x8*)&SM[(mt * 16 + l15) * 72 + 32 + q * 8];
        #pragma unroll
        for (int rt = 0; rt < 4; rt++) {
          f32x4 acc = {}; acc = MFMA(a0, bk[rt][0], acc); acc = MFMA(a1, bk[rt][1], acc);
          #pragma unroll
          for (int reg = 0; reg < 4; reg++)
            KT[(mt * 16 + q * 4 + reg) * 72 + rt * 16 + l15] = (f16)sigmoidf_(acc[reg]);
        }
      }
    } else {
      // VM[r][m] = sigmoid( sum_s Wv[r][s] * M^T[m][s] ), mt = (w-4)*4..
      f16x8 av[4][2];
      #pragma unroll
      for (int rt = 0; rt < 4; rt++) {
        av[rt][0] = *(const f16x8*)(Wv + (rt * 16 + l15) * 64 + q * 8);
        av[rt][1] = *(const f16x8*)(Wv + (rt * 16 + l15) * 64 + 32 + q * 8);
      }
      #pragma unroll
      for (int mi = 0; mi < 4; mi++) {
        int mt = (w - 4) * 4 + mi;
        f16x8 b0 = *(const f16x8*)&SM[(mt * 16 + l15) * 72 + q * 8];
        f16x8 b1 = *(const f16x8*)&SM[(mt * 16 + l15) * 72 + 32 + q * 8];
        #pragma unroll
        for (int rt = 0; rt < 4; rt++) {
          f32x4 acc = {}; acc = MFMA(av[rt][0], b0, acc); acc = MFMA(av[rt][1], b1, acc);
          #pragma unroll
          for (int reg = 0; reg < 4; reg++)
            VM[(rt * 16 + q * 4 + reg) * 264 + mt * 16 + l15] = (f16)sigmoidf_(acc[reg]);
        }
      }
    }
    // QT[n][r] for local rows: nt = w>>1, rt = (w&1)*2 + {0,1}
    {
      int nt = w >> 1;
      f16x8 a0 = *(const f16x8*)&SM[(n0 + nt * 16 + l15) * 72 + q * 8];
      f16x8 a1 = *(const f16x8*)&SM[(n0 + nt * 16 + l15) * 72 + 32 + q * 8];
      #pragma unroll
      for (int j = 0; j < 2; j++) {
        int rt = (w & 1) * 2 + j;
        f16x8 b0 = *(const f16x8*)(Wq + (rt * 16 + l15) * 64 + q * 8);
        f16x8 b1 = *(const f16x8*)(Wq + (rt * 16 + l15) * 64 + 32 + q * 8);
        f32x4 acc = {}; acc = MFMA(a0, b0, acc); acc = MFMA(a1, b1, acc);
        #pragma unroll
        for (int reg = 0; reg < 4; reg++)
          QT[(nt * 16 + q * 4 + reg) * 72 + rt * 16 + l15] = (f16)sigmoidf_(acc[reg]);
      }
    }
    __syncthreads();
  }

  // S = exp(QK^T * sinv): wave w -> nt = w>>1, mt = (w&1)*8 .. +7; denom via shfl+LDS atomic
  {
    int nt = w >> 1;
    f16x8 a0 = *(const f16x8*)&QT[(nt * 16 + l15) * 72 + q * 8];
    f16x8 a1 = *(const f16x8*)&QT[(nt * 16 + l15) * 72 + 32 + q * 8];
    float dsum[4] = {0.f, 0.f, 0.f, 0.f};
    #pragma unroll
    for (int mi = 0; mi < 8; mi++) {
      int mt = (w & 1) * 8 + mi;
      f16x8 b0 = *(const f16x8*)&KT[(mt * 16 + l15) * 72 + q * 8];
      f16x8 b1 = *(const f16x8*)&KT[(mt * 16 + l15) * 72 + 32 + q * 8];
      f32x4 acc = {}; acc = MFMA(a0, b0, acc); acc = MFMA(a1, b1, acc);
      #pragma unroll
      for (int reg = 0; reg < 4; reg++) {
        float e = __expf(acc[reg] * sinv);
        dsum[reg] += e;
        SM[(nt * 16 + q * 4 + reg) * 264 + mt * 16 + l15] = (f16)e;
      }
    }
    #pragma unroll
    for (int reg = 0; reg < 4; reg++) {
      #pragma unroll
      for (int mask = 1; mask < 16; mask <<= 1) dsum[reg] += __shfl_xor(dsum[reg], mask);
    }
    if (l15 == 0) {
      #pragma unroll
      for (int reg = 0; reg < 4; reg++) atomicAdd(&denomS[nt * 16 + q * 4 + reg], dsum[reg]);
    }
  }
  __syncthreads();

  // AV: o^T[n][r] = sum_m S4[n][m] VM[r][m]; normalize by 1/denom (v_rcp) -> OT
  {
    int nt = w >> 1;
    f32x4 oacc[2] = {};
    #pragma unroll
    for (int kc = 0; kc < 8; kc++) {
      f16x8 af = *(const f16x8*)&SM[(nt * 16 + l15) * 264 + kc * 32 + q * 8];
      #pragma unroll
      for (int j = 0; j < 2; j++) {
        int rt = (w & 1) * 2 + j;
        f16x8 bf = *(const f16x8*)&VM[(rt * 16 + l15) * 264 + kc * 32 + q * 8];
        oacc[j] = MFMA(af, bf, oacc[j]);
      }
    }
    float rden[4];
    #pragma unroll
    for (int reg = 0; reg < 4; reg++)
      rden[reg] = __builtin_amdgcn_rcpf(denomS[nt * 16 + q * 4 + reg]);
    #pragma unroll
    for (int j = 0; j < 2; j++) {
      int rt = (w & 1) * 2 + j;
      #pragma unroll
      for (int reg = 0; reg < 4; reg++) {
        int row = nt * 16 + q * 4 + reg;
        OT[row * 72 + rt * 16 + l15] = (f16)(oacc[j][reg] * rden[reg]);
      }
    }
  }
  __syncthreads();

  // M'[n][s] = silu( sum_r OT[n][r] Wo[s][r] ) -> Mst (QT reused, stride 64)
  f16* Mst = QT;
  {
    int nt = w >> 1;
    f16x8 a0 = *(const f16x8*)&OT[(nt * 16 + l15) * 72 + q * 8];
    f16x8 a1 = *(const f16x8*)&OT[(nt * 16 + l15) * 72 + 32 + q * 8];
    #pragma unroll
    for (int j = 0; j < 2; j++) {
      int st = (w & 1) * 2 + j;
      f16x8 b0 = *(const f16x8*)(Wo + (st * 16 + l15) * 64 + q * 8);
      f16x8 b1 = *(const f16x8*)(Wo + (st * 16 + l15) * 64 + 32 + q * 8);
      f32x4 acc = {}; acc = MFMA(a0, b0, acc); acc = MFMA(a1, b1, acc);
      #pragma unroll
      for (int reg = 0; reg < 4; reg++) {
        float z = acc[reg];
        Mst[(nt * 16 + q * 4 + reg) * 64 + st * 16 + l15] = (f16)(z * sigmoidf_(z));
      }
    }
  }
  __syncthreads();

  if (LAYER < 2) {
    int row = t >> 3, c = t & 7;
    *(uint4*)(Mout + (size_t)b * 16384 + (size_t)(n0 + row) * 64 + c * 8)
        = *(const uint4*)&Mst[row * 64 + c * 8];
  } else {
    float contrib = 0.0f;
    if (t < 64) {
      int ntok = n0 + t;
      const f16* row = &Mst[t * 64];
      float d[4] = {0, 0, 0, 0}, pp = 0.0f;
      #pragma unroll
      for (int gg = 0; gg < 8; gg++) {
        f16x8 v = *(const f16x8*)(row + gg * 8);
        float ss = 0.0f;
        #pragma unroll
        for (int k = 0; k < 8; k++) { float f = (float)v[k]; ss += f * f; }
        if (gg < 4) d[gg] = ss; else pp += ss;
      }
      int np = ntok >> 1, c0 = (ntok & 1) * 2;
      const float* xb = x + (size_t)b * 524288 + (size_t)c0 * 256;
      float q1a = xb[np], q1b = xb[256 + np];
      float q2a = xb[128 + np], q2b = xb[384 + np];
      contrib = d[0] * (q1a * q1a + q1b * q1b)
              + (d[1] + d[2]) * (q1a * q2a + q1b * q2b)
              + d[3] * (q2a * q2a + q2b * q2b) + pp;
    }
    if (w == 0) {
      #pragma unroll
      for (int off = 32; off; off >>= 1) contrib += __shfl_down(contrib, off);
      if (lane == 0) atomicAdd(out + b, contrib);
    }
  }
}

// ---------------------------------------------------------------------------
extern "C" void kernel_launch(void* const* d_in, const int* in_sizes, int n_in,
                              void* d_out, int out_size, void* d_ws, size_t ws_size,
                              hipStream_t stream) {
  const float* x   = (const float*)d_in[0];
  const float* L   = (const float*)d_in[1];
  const float* Aq  = (const float*)d_in[2];
  const float* Ak  = (const float*)d_in[3];
  const float* Av  = (const float*)d_in[4];
  const float* Aq1 = (const float*)d_in[5];
  const float* Ak1 = (const float*)d_in[6];
  const float* Av1 = (const float*)d_in[7];
  const float* Aq5 = (const float*)d_in[8];
  const float* Ak5 = (const float*)d_in[9];
  const float* Av5 = (const float*)d_in[10];
  const float* Ao  = (const float*)d_in[11];
  const float* Ao1 = (const float*)d_in[12];
  const float* Ao5 = (const float*)d_in[13];

  char* ws = (char*)d_ws;
  float* scale = (float*)ws;
  f16* Wcat  = (f16*)(ws + 256);
  f16* Wsm   = (f16*)(ws + 786688);
  f16* Qtg   = (f16*)(ws + 860416);
  f16* Ktg   = (f16*)(ws + 2957568);
  f16* Vgg   = (f16*)(ws + 5054720);
  f16* MbufA = (f16*)(ws + 7151872);
  f16* MbufB = (f16*)(ws + 9249024);
  float* out = (float*)d_out;

  prep_kernel<<<170, 256, 0, stream>>>(L, Aq, Ak, Av, Aq1, Ak1, Av1,
                                       Aq5, Ak5, Av5, Ao, Ao1, Ao5, scale, Wcat, Wsm, out);
  qkv1_kernel<<<dim3(8, 64), 256, 0, stream>>>(x, Wcat, Qtg, Ktg, Vgg);
  attnB_kernel<0><<<dim3(4, 64), 512, 0, stream>>>(x, scale, Wsm, Qtg, Ktg, Vgg,
                                                   nullptr, MbufA, out);
  attnB_kernel<1><<<dim3(4, 64), 512, 0, stream>>>(x, scale, Wsm, Qtg, Ktg, Vgg,
                                                   MbufA, MbufB, out);
  attnB_kernel<2><<<dim3(4, 64), 512, 0, stream>>>(x, scale, Wsm, Qtg, Ktg, Vgg,
                                                   MbufB, nullptr, out);
}